// Round 1
// baseline (640.071 us; speedup 1.0000x reference)
//
#include <hip/hip_runtime.h>
#include <stdint.h>

#define NB 4
#define NH 8
#define SS 2048
#define EE 512
#define DD 64
#define MM (NB*SS)      // 8192
#define LDP 72          // padded LDS row (bf16 elems): 144B = 36 banks -> ~2-way max

typedef __attribute__((ext_vector_type(8))) __bf16 bf16x8;
typedef __attribute__((ext_vector_type(8))) unsigned short ushort8;
typedef __attribute__((ext_vector_type(4))) unsigned short ushort4v;
typedef __attribute__((ext_vector_type(4))) float f32x4;

__device__ __forceinline__ uint16_t f2bf(float f) {
    union { float f; uint32_t u; } v; v.f = f;
    return (uint16_t)((v.u + 0x7fffu + ((v.u >> 16) & 1u)) >> 16);   // RNE
}
__device__ __forceinline__ float bf2f(uint16_t h) {
    union { uint32_t u; float f; } v; v.u = ((uint32_t)h) << 16;
    return v.f;
}

// ---------------- split fp32 -> bf16 hi + bf16 lo ----------------
__global__ __launch_bounds__(256) void split_k(const float* __restrict__ in,
        uint16_t* __restrict__ hi, uint16_t* __restrict__ lo, int n4) {
    int i = blockIdx.x * 256 + threadIdx.x;
    if (i >= n4) return;
    f32x4 x = reinterpret_cast<const f32x4*>(in)[i];
    ushort4v h, l;
#pragma unroll
    for (int j = 0; j < 4; j++) {
        uint16_t hh = f2bf(x[j]);
        h[j] = hh;
        l[j] = f2bf(x[j] - bf2f(hh));
    }
    reinterpret_cast<ushort4v*>(hi)[i] = h;
    reinterpret_cast<ushort4v*>(lo)[i] = l;
}

// ---------------- split-bf16 3-pass NT GEMM: C = alpha*(A@B^T + bias) ----------------
// A: [Mtot x K] as hi/lo bf16, B: [N x K] as hi/lo bf16 (row-major, K contiguous)
// mode 0: write split bf16 pair in head layout [b,h,s,d]
// mode 1: write single bf16 in head layout
// mode 2: write fp32 row-major [m][N]
__global__ __launch_bounds__(256, 2)
void gemm_nt(const uint16_t* __restrict__ Ah, const uint16_t* __restrict__ Al,
             const uint16_t* __restrict__ Bh, const uint16_t* __restrict__ Bl,
             const float* __restrict__ bias, float alpha, int K, int N, int mode,
             uint16_t* __restrict__ Oh, uint16_t* __restrict__ Ol, float* __restrict__ Of)
{
    __shared__ uint16_t sAh[128*LDP], sAl[128*LDP], sBh[128*LDP], sBl[128*LDP];
    const int t = threadIdx.x;
    const int lane = t & 63;
    const int wave = t >> 6;
    const int m0 = blockIdx.x * 128;
    const int n0 = blockIdx.y * 128;

    f32x4 zero = {0.f, 0.f, 0.f, 0.f};
    f32x4 acc[4][4];
#pragma unroll
    for (int i = 0; i < 4; i++)
#pragma unroll
        for (int j = 0; j < 4; j++) acc[i][j] = zero;

    const int sr = t >> 3;        // 0..31
    const int sc = (t & 7) * 8;   // 0..56

    for (int k0 = 0; k0 < K; k0 += 64) {
#pragma unroll
        for (int p = 0; p < 4; p++) {
            const int row = sr + 32 * p;
            const size_t ga = (size_t)(m0 + row) * K + k0 + sc;
            const size_t gb = (size_t)(n0 + row) * K + k0 + sc;
            *reinterpret_cast<ushort8*>(&sAh[row*LDP + sc]) = *reinterpret_cast<const ushort8*>(&Ah[ga]);
            *reinterpret_cast<ushort8*>(&sAl[row*LDP + sc]) = *reinterpret_cast<const ushort8*>(&Al[ga]);
            *reinterpret_cast<ushort8*>(&sBh[row*LDP + sc]) = *reinterpret_cast<const ushort8*>(&Bh[gb]);
            *reinterpret_cast<ushort8*>(&sBl[row*LDP + sc]) = *reinterpret_cast<const ushort8*>(&Bl[gb]);
        }
        __syncthreads();
        const int mw = (wave >> 1) * 64;
        const int nw = (wave & 1) * 64;
#pragma unroll
        for (int ks = 0; ks < 2; ks++) {
            const int kk = ks*32 + (lane >> 4) * 8;
            bf16x8 fah[4], fal[4], fbh[4], fbl[4];
#pragma unroll
            for (int i = 0; i < 4; i++) {
                const int ra = (mw + 16*i + (lane & 15)) * LDP + kk;
                fah[i] = *reinterpret_cast<const bf16x8*>(&sAh[ra]);
                fal[i] = *reinterpret_cast<const bf16x8*>(&sAl[ra]);
                const int rb = (nw + 16*i + (lane & 15)) * LDP + kk;
                fbh[i] = *reinterpret_cast<const bf16x8*>(&sBh[rb]);
                fbl[i] = *reinterpret_cast<const bf16x8*>(&sBl[rb]);
            }
#pragma unroll
            for (int i = 0; i < 4; i++)
#pragma unroll
                for (int j = 0; j < 4; j++) {
                    acc[i][j] = __builtin_amdgcn_mfma_f32_16x16x32_bf16(fah[i], fbh[j], acc[i][j], 0, 0, 0);
                    acc[i][j] = __builtin_amdgcn_mfma_f32_16x16x32_bf16(fah[i], fbl[j], acc[i][j], 0, 0, 0);
                    acc[i][j] = __builtin_amdgcn_mfma_f32_16x16x32_bf16(fal[i], fbh[j], acc[i][j], 0, 0, 0);
                }
        }
        __syncthreads();
    }

    const int mw = (wave >> 1) * 64;
    const int nw = (wave & 1) * 64;
#pragma unroll
    for (int j = 0; j < 4; j++) {
        const int col = n0 + nw + 16*j + (lane & 15);
        const float bv = bias ? bias[col] : 0.f;
#pragma unroll
        for (int i = 0; i < 4; i++) {
            const int rowb = m0 + mw + 16*i + ((lane >> 4) << 2);
#pragma unroll
            for (int r4 = 0; r4 < 4; r4++) {
                const int m = rowb + r4;
                const float val = (acc[i][j][r4] + bv) * alpha;
                if (mode == 2) {
                    Of[(size_t)m * N + col] = val;
                } else {
                    const int bb = m >> 11, s = m & (SS-1), h = col >> 6, d = col & 63;
                    const size_t idx = (((size_t)(bb*NH + h)) * SS + s) * DD + d;
                    const uint16_t hh = f2bf(val);
                    Oh[idx] = hh;
                    if (mode == 0) Ol[idx] = f2bf(val - bf2f(hh));
                }
            }
        }
    }
}

// ---------------- raw scores: S = Qs @ K^T  (Q pre-scaled by 1/8), split 3-pass ----------------
__global__ __launch_bounds__(256, 2)
void scores_k(const uint16_t* __restrict__ Qh, const uint16_t* __restrict__ Ql,
              const uint16_t* __restrict__ Kh, const uint16_t* __restrict__ Kl,
              float* __restrict__ attn)
{
    __shared__ uint16_t sQh[128*LDP], sQl[128*LDP], sKh[128*LDP], sKl[128*LDP];
    const int t = threadIdx.x, lane = t & 63, wave = t >> 6;
    const int kt = blockIdx.x, qt = blockIdx.y, bh = blockIdx.z;
    const size_t hb = (size_t)bh * SS * DD;

    const int sr = t >> 3, sc = (t & 7) * 8;
#pragma unroll
    for (int p = 0; p < 4; p++) {
        const int row = sr + 32 * p;
        const size_t gq = hb + (size_t)(qt*128 + row) * DD + sc;
        const size_t gk = hb + (size_t)(kt*128 + row) * DD + sc;
        *reinterpret_cast<ushort8*>(&sQh[row*LDP + sc]) = *reinterpret_cast<const ushort8*>(&Qh[gq]);
        *reinterpret_cast<ushort8*>(&sQl[row*LDP + sc]) = *reinterpret_cast<const ushort8*>(&Ql[gq]);
        *reinterpret_cast<ushort8*>(&sKh[row*LDP + sc]) = *reinterpret_cast<const ushort8*>(&Kh[gk]);
        *reinterpret_cast<ushort8*>(&sKl[row*LDP + sc]) = *reinterpret_cast<const ushort8*>(&Kl[gk]);
    }
    __syncthreads();

    f32x4 zero = {0.f, 0.f, 0.f, 0.f};
    f32x4 acc[4][4];
#pragma unroll
    for (int i = 0; i < 4; i++)
#pragma unroll
        for (int j = 0; j < 4; j++) acc[i][j] = zero;

    const int mw = (wave >> 1) * 64;
    const int nw = (wave & 1) * 64;
#pragma unroll
    for (int ks = 0; ks < 2; ks++) {
        const int kk = ks*32 + (lane >> 4) * 8;
        bf16x8 fah[4], fal[4], fbh[4], fbl[4];
#pragma unroll
        for (int i = 0; i < 4; i++) {
            const int ra = (mw + 16*i + (lane & 15)) * LDP + kk;
            fah[i] = *reinterpret_cast<const bf16x8*>(&sQh[ra]);
            fal[i] = *reinterpret_cast<const bf16x8*>(&sQl[ra]);
            const int rb = (nw + 16*i + (lane & 15)) * LDP + kk;
            fbh[i] = *reinterpret_cast<const bf16x8*>(&sKh[rb]);
            fbl[i] = *reinterpret_cast<const bf16x8*>(&sKl[rb]);
        }
#pragma unroll
        for (int i = 0; i < 4; i++)
#pragma unroll
            for (int j = 0; j < 4; j++) {
                acc[i][j] = __builtin_amdgcn_mfma_f32_16x16x32_bf16(fah[i], fbh[j], acc[i][j], 0, 0, 0);
                acc[i][j] = __builtin_amdgcn_mfma_f32_16x16x32_bf16(fah[i], fbl[j], acc[i][j], 0, 0, 0);
                acc[i][j] = __builtin_amdgcn_mfma_f32_16x16x32_bf16(fal[i], fbh[j], acc[i][j], 0, 0, 0);
            }
    }

    float* outp = attn + ((size_t)bh * SS + qt*128) * SS + (size_t)kt * 128;
#pragma unroll
    for (int i = 0; i < 4; i++)
#pragma unroll
        for (int j = 0; j < 4; j++)
#pragma unroll
            for (int r4 = 0; r4 < 4; r4++) {
                const int rrow = mw + 16*i + ((lane >> 4) << 2) + r4;
                const int ccol = nw + 16*j + (lane & 15);
                outp[(size_t)rrow * SS + ccol] = acc[i][j][r4];
            }
}

// ---------------- softmax (in-place raw->weights in d_out) + PV ----------------
__global__ __launch_bounds__(256, 2)
void pv_k(float* __restrict__ attn, const uint16_t* __restrict__ Vh,
          uint16_t* __restrict__ Oh, uint16_t* __restrict__ Ol)
{
    __shared__ float rmax[128], rinv[128];
    __shared__ uint16_t wt[128*LDP];
    __shared__ uint16_t vt[64*LDP];
    const int t = threadIdx.x, lane = t & 63, wave = t >> 6;
    const int qt = blockIdx.x, bh = blockIdx.y;
    float* sptr = attn + ((size_t)bh * SS + qt*128) * SS;
    const uint16_t* vsrc = Vh + (size_t)bh * SS * DD;

    // ---- pass 1: per-row online max & sum(exp) over 2048 cols ----
    const int rg16 = t >> 4;   // 0..15
    const int cg   = t & 15;   // 0..15 (16 lanes per row)
    for (int rc = 0; rc < 8; rc++) {
        const int row = rc*16 + rg16;
        const float* rp = sptr + (size_t)row * SS;
        float m = -3.0e38f, ssum = 0.f;
#pragma unroll 4
        for (int ci = 0; ci < 32; ci++) {
            f32x4 s4 = *reinterpret_cast<const f32x4*>(&rp[cg*4 + ci*64]);
#pragma unroll
            for (int e = 0; e < 4; e++) {
                const float xv = s4[e];
                const float nm = fmaxf(m, xv);
                ssum = ssum * __expf(m - nm) + __expf(xv - nm);
                m = nm;
            }
        }
#pragma unroll
        for (int o = 1; o < 16; o <<= 1) {
            const float om = __shfl_xor(m, o);
            const float os = __shfl_xor(ssum, o);
            const float nm = fmaxf(m, om);
            ssum = ssum * __expf(m - nm) + os * __expf(om - nm);
            m = nm;
        }
        if (cg == 0) { rmax[row] = m; rinv[row] = 1.0f / ssum; }
    }
    __syncthreads();

    f32x4 zero = {0.f, 0.f, 0.f, 0.f};
    f32x4 acc[2][4];
#pragma unroll
    for (int i = 0; i < 2; i++)
#pragma unroll
        for (int j = 0; j < 4; j++) acc[i][j] = zero;

    const int rr = t >> 2;     // 0..63
    const int fb = t & 3;
    for (int c64 = 0; c64 < 32; c64++) {
        // normalize chunk [128 x 64]: write final weights to d_out, bf16 copy to LDS
#pragma unroll
        for (int sub = 0; sub < 2; sub++) {
            const int row = rr + 64*sub;
            const float rm = rmax[row], ri = rinv[row];
            float* rp = sptr + (size_t)row * SS + c64*64;
#pragma unroll
            for (int fi = 0; fi < 4; fi++) {
                const int col = (fb*4 + fi) * 4;
                f32x4 s4 = *reinterpret_cast<const f32x4*>(&rp[col]);
                f32x4 w4;
#pragma unroll
                for (int e = 0; e < 4; e++) w4[e] = __expf(s4[e] - rm) * ri;
                *reinterpret_cast<f32x4*>(&rp[col]) = w4;
                ushort4v wb;
#pragma unroll
                for (int e = 0; e < 4; e++) wb[e] = f2bf(w4[e]);
                *reinterpret_cast<ushort4v*>(&wt[row*LDP + col]) = wb;
            }
        }
        // stage V chunk transposed: vt[d][t']
        {
            const int tv = t >> 2;
#pragma unroll
            for (int u = 0; u < 2; u++) {
                const int dbase = (t & 3) * 16 + u * 8;
                ushort8 v8 = *reinterpret_cast<const ushort8*>(&vsrc[(size_t)(c64*64 + tv) * DD + dbase]);
#pragma unroll
                for (int e = 0; e < 8; e++) vt[(dbase + e)*LDP + tv] = v8[e];
            }
        }
        __syncthreads();
        const int mwv = wave * 32;
#pragma unroll
        for (int ks = 0; ks < 2; ks++) {
            const int kk = ks*32 + (lane >> 4) * 8;
            bf16x8 afr[2], bfr[4];
#pragma unroll
            for (int i = 0; i < 2; i++)
                afr[i] = *reinterpret_cast<const bf16x8*>(&wt[(mwv + 16*i + (lane & 15))*LDP + kk]);
#pragma unroll
            for (int j = 0; j < 4; j++)
                bfr[j] = *reinterpret_cast<const bf16x8*>(&vt[(16*j + (lane & 15))*LDP + kk]);
#pragma unroll
            for (int i = 0; i < 2; i++)
#pragma unroll
                for (int j = 0; j < 4; j++)
                    acc[i][j] = __builtin_amdgcn_mfma_f32_16x16x32_bf16(afr[i], bfr[j], acc[i][j], 0, 0, 0);
        }
        __syncthreads();
    }

    // epilogue: attn_output split-bf16 into [b, s, h*64+d]
    const int b = bh >> 3, h = bh & 7;
#pragma unroll
    for (int i = 0; i < 2; i++)
#pragma unroll
        for (int j = 0; j < 4; j++)
#pragma unroll
            for (int r4 = 0; r4 < 4; r4++) {
                const int srow = qt*128 + wave*32 + 16*i + ((lane >> 4) << 2) + r4;
                const int col = h*64 + 16*j + (lane & 15);
                const size_t idx = ((size_t)b * SS + srow) * (size_t)EE + col;
                const float val = acc[i][j][r4];
                const uint16_t hh = f2bf(val);
                Oh[idx] = hh;
                Ol[idx] = f2bf(val - bf2f(hh));
            }
}

extern "C" void kernel_launch(void* const* d_in, const int* in_sizes, int n_in,
                              void* d_out, int out_size, void* d_ws, size_t ws_size,
                              hipStream_t stream)
{
    const float* x  = (const float*)d_in[0];
    const float* Wq = (const float*)d_in[1];
    const float* bq = (const float*)d_in[2];
    const float* Wk = (const float*)d_in[3];
    const float* bk = (const float*)d_in[4];
    const float* Wv = (const float*)d_in[5];
    const float* bv = (const float*)d_in[6];
    const float* Wo = (const float*)d_in[7];
    const float* bo = (const float*)d_in[8];

    float* outF = (float*)d_out;
    float* attn = outF + (size_t)MM * EE;   // output 1 region (also raw-score scratch)

    const size_t NXE = (size_t)MM * EE;     // 4,194,304
    const size_t NW  = (size_t)EE * EE;     // 262,144
    uint16_t* p = (uint16_t*)d_ws;
    uint16_t* xh  = p;            p += NXE;
    uint16_t* xl  = p;            p += NXE;
    uint16_t* wqh = p;            p += NW;
    uint16_t* wql = p;            p += NW;
    uint16_t* wkh = p;            p += NW;
    uint16_t* wkl = p;            p += NW;
    uint16_t* wvh = p;            p += NW;
    uint16_t* wvl = p;            p += NW;
    uint16_t* woh = p;            p += NW;
    uint16_t* wol = p;            p += NW;
    uint16_t* qh  = p;            p += NXE;
    uint16_t* ql  = p;            p += NXE;
    uint16_t* kh  = p;            p += NXE;
    uint16_t* kl  = p;            p += NXE;
    uint16_t* vh  = p;            p += NXE;
    uint16_t* ah  = p;            p += NXE;
    uint16_t* al  = p;            p += NXE;

    split_k<<<(int)((NXE/4 + 255)/256), 256, 0, stream>>>(x,  xh,  xl,  (int)(NXE/4));
    split_k<<<(int)((NW /4 + 255)/256), 256, 0, stream>>>(Wq, wqh, wql, (int)(NW/4));
    split_k<<<(int)((NW /4 + 255)/256), 256, 0, stream>>>(Wk, wkh, wkl, (int)(NW/4));
    split_k<<<(int)((NW /4 + 255)/256), 256, 0, stream>>>(Wv, wvh, wvl, (int)(NW/4));
    split_k<<<(int)((NW /4 + 255)/256), 256, 0, stream>>>(Wo, woh, wol, (int)(NW/4));

    dim3 g(MM/128, EE/128);
    // Q scaled by 1/8 (folds 1/sqrt(64) into projection, incl. bias)
    gemm_nt<<<g, 256, 0, stream>>>(xh, xl, wqh, wql, bq, 0.125f, EE, EE, 0, qh, ql, nullptr);
    gemm_nt<<<g, 256, 0, stream>>>(xh, xl, wkh, wkl, bk, 1.0f,   EE, EE, 0, kh, kl, nullptr);
    gemm_nt<<<g, 256, 0, stream>>>(xh, xl, wvh, wvl, bv, 1.0f,   EE, EE, 1, vh, nullptr, nullptr);

    scores_k<<<dim3(SS/128, SS/128, NB*NH), 256, 0, stream>>>(qh, ql, kh, kl, attn);
    pv_k<<<dim3(SS/128, NB*NH), 256, 0, stream>>>(attn, vh, ah, al);

    gemm_nt<<<g, 256, 0, stream>>>(ah, al, woh, wol, bo, 1.0f, EE, EE, 2, nullptr, nullptr, outF);
}

// Round 2
// 356.982 us; speedup vs baseline: 1.7930x; 1.7930x over previous
//
#include <hip/hip_runtime.h>
#include <stdint.h>

#define NB 4
#define NH 8
#define SS 2048
#define EE 512
#define DD 64
#define MM (NB*SS)      // 8192
#define LDP 72          // padded LDS row (bf16 elems) for K-dim-64 tiles
#define LDW 136         // padded LDS row for 128-wide W / V^T tiles

typedef __attribute__((ext_vector_type(8))) __bf16 bf16x8;
typedef __attribute__((ext_vector_type(8))) unsigned short ushort8;
typedef __attribute__((ext_vector_type(4))) unsigned short ushort4v;
typedef __attribute__((ext_vector_type(4))) float f32x4;

__device__ __forceinline__ uint16_t f2bf(float f) {
    union { float f; uint32_t u; } v; v.f = f;
    return (uint16_t)((v.u + 0x7fffu + ((v.u >> 16) & 1u)) >> 16);   // RNE
}
__device__ __forceinline__ float bf2f(uint16_t h) {
    union { uint32_t u; float f; } v; v.u = ((uint32_t)h) << 16;
    return v.f;
}

// ---------------- split fp32 -> bf16 hi + bf16 lo ----------------
__global__ __launch_bounds__(256) void split_k(const float* __restrict__ in,
        uint16_t* __restrict__ hi, uint16_t* __restrict__ lo, int n4) {
    int i = blockIdx.x * 256 + threadIdx.x;
    if (i >= n4) return;
    f32x4 x = reinterpret_cast<const f32x4*>(in)[i];
    ushort4v h, l;
#pragma unroll
    for (int j = 0; j < 4; j++) {
        uint16_t hh = f2bf(x[j]);
        h[j] = hh;
        l[j] = f2bf(x[j] - bf2f(hh));
    }
    reinterpret_cast<ushort4v*>(hi)[i] = h;
    reinterpret_cast<ushort4v*>(lo)[i] = l;
}

// ---------------- split-bf16 3-pass NT GEMM: C = alpha*(A@B^T + bias) ----------------
__global__ __launch_bounds__(256, 2)
void gemm_nt(const uint16_t* __restrict__ Ah, const uint16_t* __restrict__ Al,
             const uint16_t* __restrict__ Bh, const uint16_t* __restrict__ Bl,
             const float* __restrict__ bias, float alpha, int K, int N, int mode,
             uint16_t* __restrict__ Oh, uint16_t* __restrict__ Ol, float* __restrict__ Of)
{
    __shared__ uint16_t sAh[128*LDP], sAl[128*LDP], sBh[128*LDP], sBl[128*LDP];
    const int t = threadIdx.x;
    const int lane = t & 63;
    const int wave = t >> 6;
    const int m0 = blockIdx.x * 128;
    const int n0 = blockIdx.y * 128;

    f32x4 zero = {0.f, 0.f, 0.f, 0.f};
    f32x4 acc[4][4];
#pragma unroll
    for (int i = 0; i < 4; i++)
#pragma unroll
        for (int j = 0; j < 4; j++) acc[i][j] = zero;

    const int sr = t >> 3;        // 0..31
    const int sc = (t & 7) * 8;   // 0..56

    for (int k0 = 0; k0 < K; k0 += 64) {
#pragma unroll
        for (int p = 0; p < 4; p++) {
            const int row = sr + 32 * p;
            const size_t ga = (size_t)(m0 + row) * K + k0 + sc;
            const size_t gb = (size_t)(n0 + row) * K + k0 + sc;
            *reinterpret_cast<ushort8*>(&sAh[row*LDP + sc]) = *reinterpret_cast<const ushort8*>(&Ah[ga]);
            *reinterpret_cast<ushort8*>(&sAl[row*LDP + sc]) = *reinterpret_cast<const ushort8*>(&Al[ga]);
            *reinterpret_cast<ushort8*>(&sBh[row*LDP + sc]) = *reinterpret_cast<const ushort8*>(&Bh[gb]);
            *reinterpret_cast<ushort8*>(&sBl[row*LDP + sc]) = *reinterpret_cast<const ushort8*>(&Bl[gb]);
        }
        __syncthreads();
        const int mw = (wave >> 1) * 64;
        const int nw = (wave & 1) * 64;
#pragma unroll
        for (int ks = 0; ks < 2; ks++) {
            const int kk = ks*32 + (lane >> 4) * 8;
            bf16x8 fah[4], fal[4], fbh[4], fbl[4];
#pragma unroll
            for (int i = 0; i < 4; i++) {
                const int ra = (mw + 16*i + (lane & 15)) * LDP + kk;
                fah[i] = *reinterpret_cast<const bf16x8*>(&sAh[ra]);
                fal[i] = *reinterpret_cast<const bf16x8*>(&sAl[ra]);
                const int rb = (nw + 16*i + (lane & 15)) * LDP + kk;
                fbh[i] = *reinterpret_cast<const bf16x8*>(&sBh[rb]);
                fbl[i] = *reinterpret_cast<const bf16x8*>(&sBl[rb]);
            }
#pragma unroll
            for (int i = 0; i < 4; i++)
#pragma unroll
                for (int j = 0; j < 4; j++) {
                    acc[i][j] = __builtin_amdgcn_mfma_f32_16x16x32_bf16(fah[i], fbh[j], acc[i][j], 0, 0, 0);
                    acc[i][j] = __builtin_amdgcn_mfma_f32_16x16x32_bf16(fah[i], fbl[j], acc[i][j], 0, 0, 0);
                    acc[i][j] = __builtin_amdgcn_mfma_f32_16x16x32_bf16(fal[i], fbh[j], acc[i][j], 0, 0, 0);
                }
        }
        __syncthreads();
    }

    const int mw = (wave >> 1) * 64;
    const int nw = (wave & 1) * 64;
#pragma unroll
    for (int j = 0; j < 4; j++) {
        const int col = n0 + nw + 16*j + (lane & 15);
        const float bv = bias ? bias[col] : 0.f;
#pragma unroll
        for (int i = 0; i < 4; i++) {
            const int rowb = m0 + mw + 16*i + ((lane >> 4) << 2);
#pragma unroll
            for (int r4 = 0; r4 < 4; r4++) {
                const int m = rowb + r4;
                const float val = (acc[i][j][r4] + bv) * alpha;
                if (mode == 2) {
                    Of[(size_t)m * N + col] = val;
                } else {
                    const int bb = m >> 11, s = m & (SS-1), h = col >> 6, d = col & 63;
                    const size_t idx = (((size_t)(bb*NH + h)) * SS + s) * DD + d;
                    const uint16_t hh = f2bf(val);
                    Oh[idx] = hh;
                    if (mode == 0) Ol[idx] = f2bf(val - bf2f(hh));
                }
            }
        }
    }
}

// ---------------- fused flash attention: QK^T (split, recomputed) + softmax + weights write + PV ----------------
// Q pre-scaled by 0.125*log2(e), so scores are in log2 units: softmax via exp2.
__global__ __launch_bounds__(256, 2)
void attn_fused(const uint16_t* __restrict__ Qh, const uint16_t* __restrict__ Ql,
                const uint16_t* __restrict__ Kh, const uint16_t* __restrict__ Kl,
                const uint16_t* __restrict__ Vh,
                float* __restrict__ attn,
                uint16_t* __restrict__ Oh, uint16_t* __restrict__ Ol)
{
    __shared__ uint16_t smem[128*LDP*2 + 64*LDW];
    uint16_t* skh  = smem;                 // K hi tile [128][LDP]
    uint16_t* skl  = smem + 128*LDP;       // K lo tile [128][LDP]
    uint16_t* wlds = smem;                 // overlay: W bf16 tile [128][LDW] (34816B <= 36864B)
    uint16_t* svt  = smem + 128*LDP*2;     // V^T tile [64][LDW]

    const int t = threadIdx.x, lane = t & 63, wave = t >> 6;
    const int qt = blockIdx.x, bh = blockIdx.y;
    const size_t hb = (size_t)bh * SS * DD;
    const uint16_t* kbh = Kh + hb;
    const uint16_t* kbl = Kl + hb;
    const uint16_t* vbs = Vh + hb;

    const int l15 = lane & 15;
    const int l16 = lane >> 4;
    const int sr = t >> 3;        // 0..31
    const int sc = (t & 7) * 8;   // 0..56

    // ---- Q fragments in registers (persistent) ----
    bf16x8 qfh[2][2], qfl[2][2];
#pragma unroll
    for (int i = 0; i < 2; i++)
#pragma unroll
        for (int ks = 0; ks < 2; ks++) {
            const size_t qa = hb + (size_t)(qt*128 + wave*32 + 16*i + l15) * DD + ks*32 + l16*8;
            qfh[i][ks] = *reinterpret_cast<const bf16x8*>(&Qh[qa]);
            qfl[i][ks] = *reinterpret_cast<const bf16x8*>(&Ql[qa]);
        }

    float m_run[2][4], l_run[2][4];
#pragma unroll
    for (int i = 0; i < 2; i++)
#pragma unroll
        for (int r = 0; r < 4; r++) { m_run[i][r] = -3.0e38f; l_run[i][r] = 0.f; }

    f32x4 zero = {0.f, 0.f, 0.f, 0.f};

    // ================= phase 1: online max & sum =================
    for (int kt = 0; kt < 16; kt++) {
#pragma unroll
        for (int p = 0; p < 4; p++) {
            const int row = sr + 32 * p;
            const size_t gk = (size_t)(kt*128 + row) * DD + sc;
            *reinterpret_cast<ushort8*>(&skh[row*LDP + sc]) = *reinterpret_cast<const ushort8*>(&kbh[gk]);
            *reinterpret_cast<ushort8*>(&skl[row*LDP + sc]) = *reinterpret_cast<const ushort8*>(&kbl[gk]);
        }
        __syncthreads();

        f32x4 accs[2][8];
#pragma unroll
        for (int i = 0; i < 2; i++)
#pragma unroll
            for (int j = 0; j < 8; j++) accs[i][j] = zero;

#pragma unroll
        for (int ks = 0; ks < 2; ks++) {
            const int kk = ks*32 + l16*8;
#pragma unroll
            for (int j = 0; j < 8; j++) {
                const int rb = (16*j + l15) * LDP + kk;
                bf16x8 fbh = *reinterpret_cast<const bf16x8*>(&skh[rb]);
                bf16x8 fbl = *reinterpret_cast<const bf16x8*>(&skl[rb]);
#pragma unroll
                for (int i = 0; i < 2; i++) {
                    accs[i][j] = __builtin_amdgcn_mfma_f32_16x16x32_bf16(qfh[i][ks], fbh, accs[i][j], 0, 0, 0);
                    accs[i][j] = __builtin_amdgcn_mfma_f32_16x16x32_bf16(qfh[i][ks], fbl, accs[i][j], 0, 0, 0);
                    accs[i][j] = __builtin_amdgcn_mfma_f32_16x16x32_bf16(qfl[i][ks], fbh, accs[i][j], 0, 0, 0);
                }
            }
        }

#pragma unroll
        for (int i = 0; i < 2; i++)
#pragma unroll
            for (int r = 0; r < 4; r++) {
                float tm = accs[i][0][r];
#pragma unroll
                for (int j = 1; j < 8; j++) tm = fmaxf(tm, accs[i][j][r]);
#pragma unroll
                for (int o = 1; o < 16; o <<= 1) tm = fmaxf(tm, __shfl_xor(tm, o));
                const float mn = fmaxf(m_run[i][r], tm);
                const float c = __builtin_amdgcn_exp2f(m_run[i][r] - mn);
                float ps = 0.f;
#pragma unroll
                for (int j = 0; j < 8; j++) ps += __builtin_amdgcn_exp2f(accs[i][j][r] - mn);
                l_run[i][r] = l_run[i][r] * c + ps;
                m_run[i][r] = mn;
            }
        __syncthreads();
    }

    // finalize: full-row sums (identical m across the 16-lane group already)
#pragma unroll
    for (int i = 0; i < 2; i++)
#pragma unroll
        for (int r = 0; r < 4; r++) {
            float s = l_run[i][r];
#pragma unroll
            for (int o = 1; o < 16; o <<= 1) s += __shfl_xor(s, o);
            l_run[i][r] = 1.0f / s;
        }

    f32x4 acco[2][4];
#pragma unroll
    for (int i = 0; i < 2; i++)
#pragma unroll
        for (int j = 0; j < 4; j++) acco[i][j] = zero;

    float* wbase = attn + ((size_t)bh * SS + qt*128) * SS;

    // ================= phase 2: recompute, write weights, PV =================
    for (int kt = 0; kt < 16; kt++) {
#pragma unroll
        for (int p = 0; p < 4; p++) {
            const int row = sr + 32 * p;
            const size_t gk = (size_t)(kt*128 + row) * DD + sc;
            *reinterpret_cast<ushort8*>(&skh[row*LDP + sc]) = *reinterpret_cast<const ushort8*>(&kbh[gk]);
            *reinterpret_cast<ushort8*>(&skl[row*LDP + sc]) = *reinterpret_cast<const ushort8*>(&kbl[gk]);
        }
        // stage V^T tile [64 d][128 k]
        {
            const int tv0 = t >> 2;
#pragma unroll
            for (int kk2 = 0; kk2 < 2; kk2++) {
                const int tv = tv0 + kk2*64;
#pragma unroll
                for (int u = 0; u < 2; u++) {
                    const int dbase = (t & 3) * 16 + u * 8;
                    ushort8 v8 = *reinterpret_cast<const ushort8*>(&vbs[(size_t)(kt*128 + tv) * DD + dbase]);
#pragma unroll
                    for (int e = 0; e < 8; e++) svt[(dbase + e)*LDW + tv] = v8[e];
                }
            }
        }
        __syncthreads();

        f32x4 accs[2][8];
#pragma unroll
        for (int i = 0; i < 2; i++)
#pragma unroll
            for (int j = 0; j < 8; j++) accs[i][j] = zero;

#pragma unroll
        for (int ks = 0; ks < 2; ks++) {
            const int kk = ks*32 + l16*8;
#pragma unroll
            for (int j = 0; j < 8; j++) {
                const int rb = (16*j + l15) * LDP + kk;
                bf16x8 fbh = *reinterpret_cast<const bf16x8*>(&skh[rb]);
                bf16x8 fbl = *reinterpret_cast<const bf16x8*>(&skl[rb]);
#pragma unroll
                for (int i = 0; i < 2; i++) {
                    accs[i][j] = __builtin_amdgcn_mfma_f32_16x16x32_bf16(qfh[i][ks], fbh, accs[i][j], 0, 0, 0);
                    accs[i][j] = __builtin_amdgcn_mfma_f32_16x16x32_bf16(qfh[i][ks], fbl, accs[i][j], 0, 0, 0);
                    accs[i][j] = __builtin_amdgcn_mfma_f32_16x16x32_bf16(qfl[i][ks], fbh, accs[i][j], 0, 0, 0);
                }
            }
        }

        // normalized weights: fp32 to global (final output), keep in regs for LDS pass
#pragma unroll
        for (int i = 0; i < 2; i++)
#pragma unroll
            for (int r = 0; r < 4; r++) {
                const float mf = m_run[i][r], iv = l_run[i][r];
                const int row = wave*32 + 16*i + l16*4 + r;
                float* wout = wbase + (size_t)row * SS + kt*128 + l15;
#pragma unroll
                for (int j = 0; j < 8; j++) {
                    const float w = __builtin_amdgcn_exp2f(accs[i][j][r] - mf) * iv;
                    accs[i][j][r] = w;
                    wout[16*j] = w;
                }
            }
        __syncthreads();   // all waves done reading K LDS

        // W bf16 into LDS (overlays K tile)
#pragma unroll
        for (int i = 0; i < 2; i++)
#pragma unroll
            for (int r = 0; r < 4; r++) {
                const int row = wave*32 + 16*i + l16*4 + r;
#pragma unroll
                for (int j = 0; j < 8; j++)
                    wlds[row*LDW + l15 + 16*j] = f2bf(accs[i][j][r]);
            }
        __syncthreads();

        // PV: O += W @ V
#pragma unroll
        for (int ks = 0; ks < 4; ks++) {
            const int kk = ks*32 + l16*8;
            bf16x8 wa[2], vbf[4];
#pragma unroll
            for (int i = 0; i < 2; i++)
                wa[i] = *reinterpret_cast<const bf16x8*>(&wlds[(wave*32 + 16*i + l15)*LDW + kk]);
#pragma unroll
            for (int j = 0; j < 4; j++)
                vbf[j] = *reinterpret_cast<const bf16x8*>(&svt[(16*j + l15)*LDW + kk]);
#pragma unroll
            for (int i = 0; i < 2; i++)
#pragma unroll
                for (int j = 0; j < 4; j++)
                    acco[i][j] = __builtin_amdgcn_mfma_f32_16x16x32_bf16(wa[i], vbf[j], acco[i][j], 0, 0, 0);
        }
        __syncthreads();
    }

    // epilogue: attn_output split-bf16 into [b, s, h*64+d]
    const int b = bh >> 3, h = bh & 7;
#pragma unroll
    for (int i = 0; i < 2; i++)
#pragma unroll
        for (int j = 0; j < 4; j++)
#pragma unroll
            for (int r4 = 0; r4 < 4; r4++) {
                const int srow = qt*128 + wave*32 + 16*i + (l16 << 2) + r4;
                const int col = h*64 + 16*j + l15;
                const size_t idx = ((size_t)b * SS + srow) * (size_t)EE + col;
                const float val = acco[i][j][r4];
                const uint16_t hh = f2bf(val);
                Oh[idx] = hh;
                Ol[idx] = f2bf(val - bf2f(hh));
            }
}

extern "C" void kernel_launch(void* const* d_in, const int* in_sizes, int n_in,
                              void* d_out, int out_size, void* d_ws, size_t ws_size,
                              hipStream_t stream)
{
    const float* x  = (const float*)d_in[0];
    const float* Wq = (const float*)d_in[1];
    const float* bq = (const float*)d_in[2];
    const float* Wk = (const float*)d_in[3];
    const float* bk = (const float*)d_in[4];
    const float* Wv = (const float*)d_in[5];
    const float* bv = (const float*)d_in[6];
    const float* Wo = (const float*)d_in[7];
    const float* bo = (const float*)d_in[8];

    float* outF = (float*)d_out;
    float* attn = outF + (size_t)MM * EE;   // output 1 region (normalized weights)

    const size_t NXE = (size_t)MM * EE;     // 4,194,304
    const size_t NW  = (size_t)EE * EE;     // 262,144
    uint16_t* p = (uint16_t*)d_ws;
    uint16_t* xh  = p;            p += NXE;
    uint16_t* xl  = p;            p += NXE;
    uint16_t* wqh = p;            p += NW;
    uint16_t* wql = p;            p += NW;
    uint16_t* wkh = p;            p += NW;
    uint16_t* wkl = p;            p += NW;
    uint16_t* wvh = p;            p += NW;
    uint16_t* wvl = p;            p += NW;
    uint16_t* woh = p;            p += NW;
    uint16_t* wol = p;            p += NW;
    uint16_t* qh  = p;            p += NXE;
    uint16_t* ql  = p;            p += NXE;
    uint16_t* kh  = p;            p += NXE;
    uint16_t* kl  = p;            p += NXE;
    uint16_t* vh  = p;            p += NXE;
    uint16_t* ah  = p;            p += NXE;
    uint16_t* al  = p;            p += NXE;

    split_k<<<(int)((NXE/4 + 255)/256), 256, 0, stream>>>(x,  xh,  xl,  (int)(NXE/4));
    split_k<<<(int)((NW /4 + 255)/256), 256, 0, stream>>>(Wq, wqh, wql, (int)(NW/4));
    split_k<<<(int)((NW /4 + 255)/256), 256, 0, stream>>>(Wk, wkh, wkl, (int)(NW/4));
    split_k<<<(int)((NW /4 + 255)/256), 256, 0, stream>>>(Wv, wvh, wvl, (int)(NW/4));
    split_k<<<(int)((NW /4 + 255)/256), 256, 0, stream>>>(Wo, woh, wol, (int)(NW/4));

    dim3 g(MM/128, EE/128);
    // Q scaled by 0.125*log2(e): scores land in log2 units -> softmax uses exp2 directly
    const float qscale = 0.125f * 1.44269504088896340736f;
    gemm_nt<<<g, 256, 0, stream>>>(xh, xl, wqh, wql, bq, qscale, EE, EE, 0, qh, ql, nullptr);
    gemm_nt<<<g, 256, 0, stream>>>(xh, xl, wkh, wkl, bk, 1.0f,   EE, EE, 0, kh, kl, nullptr);
    gemm_nt<<<g, 256, 0, stream>>>(xh, xl, wvh, wvl, bv, 1.0f,   EE, EE, 1, vh, nullptr, nullptr);

    attn_fused<<<dim3(SS/128, NB*NH), 256, 0, stream>>>(qh, ql, kh, kl, vh, attn, ah, al);

    gemm_nt<<<g, 256, 0, stream>>>(ah, al, woh, wol, bo, 1.0f, EE, EE, 2, nullptr, nullptr, outF);
}